// Round 2
// baseline (649.606 us; speedup 1.0000x reference)
//
#include <hip/hip_runtime.h>
#include <math.h>

#define NQ 12
#define DIM 4096
#define NGATES 36
#define NROUND 9

// GF(2)-linear LDS swizzle (bijective on 12 bits): sw(a^b) = sw(a)^sw(b)
constexpr unsigned swz(unsigned x) { return x ^ (x >> 4); }

// ---- compile-time circuit plan: CNOTs folded into GF(2) index maps ----
// M: logical index i lives at physical index M(i). CNOT(bc<-ctrl, bt<-tgt):
// M <- M*C (col bc ^= col bt), M^-1 <- C*M^-1 (row bt ^= row bc).
// Gate on logical bit b: pair mask m = M*e_b, "1"-selector = row b of M^-1.
// 4 gates per round (same layer => parity(m_j & s_i) = delta_ij exactly).
struct Round {
  unsigned s[4];       // selectors of the 4 gates
  unsigned l[4];       // sorted pivot low-masks for 4-zero-bit insertion
  unsigned cbsw8[16];  // swizzled byte offsets of the 16 coset slots
};
struct PlanT {
  Round rd[NROUND];
  unsigned zsel[NQ];
};

constexpr PlanT make_plan() {
  PlanT P{};
  unsigned Mcol[NQ] = {}, Minv[NQ] = {};
  for (int i = 0; i < NQ; ++i) { Mcol[i] = 1u << i; Minv[i] = 1u << i; }
  unsigned gm[NGATES] = {}, gs[NGATES] = {};
  int g = 0;
  for (int L = 0; L < 3; ++L) {
    for (int q = 0; q < NQ; ++q) { int b = NQ - 1 - q; gm[g] = Mcol[b]; gs[g] = Minv[b]; ++g; }
    for (int q = 0; q < NQ; ++q) {
      int bc = NQ - 1 - q, bt = NQ - 1 - ((q + 1) % NQ);
      Mcol[bc] ^= Mcol[bt];
      Minv[bt] ^= Minv[bc];
    }
  }
  for (int r = 0; r < NROUND; ++r) {
    unsigned m[4], red[4];
    for (int k = 0; k < 4; ++k) { m[k] = gm[4*r+k]; red[k] = m[k]; P.rd[r].s[k] = gs[4*r+k]; }
    // Gaussian elimination -> 4 distinct pivot bits
    for (int a = 0; a < 4; ++a) {
      unsigned p = red[a] & (0u - red[a]);
      for (int b = a + 1; b < 4; ++b) if (red[b] & p) red[b] ^= red[a];
    }
    unsigned piv[4];
    for (int a = 0; a < 4; ++a) piv[a] = red[a] & (0u - red[a]);
    for (int a = 0; a < 4; ++a)
      for (int b = a + 1; b < 4; ++b)
        if (piv[a] > piv[b]) { unsigned tp = piv[a]; piv[a] = piv[b]; piv[b] = tp; }
    for (int a = 0; a < 4; ++a) P.rd[r].l[a] = piv[a] - 1u;
    for (int d = 0; d < 16; ++d) {
      unsigned c = 0;
      for (int k = 0; k < 4; ++k) if (d & (1 << k)) c ^= m[k];
      P.rd[r].cbsw8[d] = swz(c) << 3;
    }
  }
  for (int q = 0; q < NQ; ++q) P.zsel[q] = Minv[NQ - 1 - q];
  return P;
}

constexpr PlanT PLAN = make_plan();

// ---- prep: fuse U = RZ*RY*RX per (layer,qubit) -> d_ws[288] ----
__global__ void qc_prep(const float* __restrict__ params, float* __restrict__ gates) {
  int t = threadIdx.x;
  if (t < NGATES) {
    float h1 = params[3*t+0]*0.5f, h2 = params[3*t+1]*0.5f, h3 = params[3*t+2]*0.5f;
    float c1 = cosf(h1), s1 = sinf(h1);
    float c2 = cosf(h2), s2 = sinf(h2);
    float c3 = cosf(h3), s3 = sinf(h3);
    float a00r =  c2*c1, a00i =  s2*s1;
    float a01r = -s2*c1, a01i = -c2*s1;
    float a10r =  s2*c1, a10i = -c2*s1;
    float a11r =  c2*c1, a11i = -s2*s1;
    float* u = &gates[t*8];
    u[0] = c3*a00r + s3*a00i;  u[1] = c3*a00i - s3*a00r;
    u[2] = c3*a01r + s3*a01i;  u[3] = c3*a01i - s3*a01r;
    u[4] = c3*a10r - s3*a10i;  u[5] = c3*a10i + s3*a10r;
    u[6] = c3*a11r - s3*a11i;  u[7] = c3*a11i + s3*a11r;
  }
}

__global__ __launch_bounds__(256, 5) void qc_main(
    const float* __restrict__ x, const float* __restrict__ gates,
    float* __restrict__ out) {
  __shared__ float2 sst[DIM];   // exactly 32768 B -> 5 blocks/CU
  char* sb = (char*)sst;
  float* sf = (float*)sst;
  const int t = threadIdx.x;
  const long row = blockIdx.x;

  // ---- stage x row (im=0), accumulate sum of squares ----
  const float4* x4 = (const float4*)(x + (size_t)row * DIM);
  float ssq = 0.f;
#pragma unroll
  for (int k = 0; k < 4; ++k) {
    float4 a = x4[t + 256*k];
    int j0 = 4*(t + 256*k);
    *(float2*)(sb + (swz((unsigned)j0)     << 3)) = make_float2(a.x, 0.f);
    *(float2*)(sb + (swz((unsigned)(j0+1)) << 3)) = make_float2(a.y, 0.f);
    *(float2*)(sb + (swz((unsigned)(j0+2)) << 3)) = make_float2(a.z, 0.f);
    *(float2*)(sb + (swz((unsigned)(j0+3)) << 3)) = make_float2(a.w, 0.f);
    ssq += a.x*a.x + a.y*a.y + a.z*a.z + a.w*a.w;
  }
#pragma unroll
  for (int off = 32; off > 0; off >>= 1) ssq += __shfl_down(ssq, off, 64);
  __syncthreads();

  // ---- 9 rounds of 4 generalized-bit gates; one LDS round-trip each ----
#pragma unroll
  for (int r = 0; r < NROUND; ++r) {
    unsigned j = (unsigned)t;
    j = ((j & ~PLAN.rd[r].l[0]) << 1) | (j & PLAN.rd[r].l[0]);
    j = ((j & ~PLAN.rd[r].l[1]) << 1) | (j & PLAN.rd[r].l[1]);
    j = ((j & ~PLAN.rd[r].l[2]) << 1) | (j & PLAN.rd[r].l[2]);
    j = ((j & ~PLAN.rd[r].l[3]) << 1) | (j & PLAN.rd[r].l[3]);
    // relabel (in swizzled-byte domain; swizzle is GF(2)-linear)
    unsigned adj8 = 0;
    adj8 ^= (unsigned)(-(int)(__popc(j & PLAN.rd[r].s[0]) & 1)) & PLAN.rd[r].cbsw8[1];
    adj8 ^= (unsigned)(-(int)(__popc(j & PLAN.rd[r].s[1]) & 1)) & PLAN.rd[r].cbsw8[2];
    adj8 ^= (unsigned)(-(int)(__popc(j & PLAN.rd[r].s[2]) & 1)) & PLAN.rd[r].cbsw8[4];
    adj8 ^= (unsigned)(-(int)(__popc(j & PLAN.rd[r].s[3]) & 1)) & PLAN.rd[r].cbsw8[8];
    const unsigned base8 = ((j ^ (j >> 4)) << 3) ^ adj8;

    float ar[16], ai[16];
#pragma unroll
    for (int d = 0; d < 16; ++d) {
      float2 v = *(const float2*)(sb + (base8 ^ PLAN.rd[r].cbsw8[d]));
      ar[d] = v.x; ai[d] = v.y;
    }
    const float* gp = gates + r*32;
#pragma unroll
    for (int st = 0; st < 4; ++st) {
      const float u0 = gp[st*8+0], u1 = gp[st*8+1], u2 = gp[st*8+2], u3 = gp[st*8+3];
      const float u4 = gp[st*8+4], u5 = gp[st*8+5], u6 = gp[st*8+6], u7 = gp[st*8+7];
#pragma unroll
      for (int d = 0; d < 16; ++d) {
        if (!(d & (1 << st))) {
          const int d1 = d | (1 << st);
          float a0r = ar[d], a0i = ai[d], a1r = ar[d1], a1i = ai[d1];
          ar[d]  = u0*a0r - u1*a0i + u2*a1r - u3*a1i;
          ai[d]  = u0*a0i + u1*a0r + u2*a1i + u3*a1r;
          ar[d1] = u4*a0r - u5*a0i + u6*a1r - u7*a1i;
          ai[d1] = u4*a0i + u5*a0r + u6*a1i + u7*a1r;
        }
      }
    }
#pragma unroll
    for (int d = 0; d < 16; ++d)
      *(float2*)(sb + (base8 ^ PLAN.rd[r].cbsw8[d])) = make_float2(ar[d], ai[d]);
    __syncthreads();
  }

  // ---- measurement: 16 consecutive amps/thread, WHT over low 4 bits ----
  const unsigned mbase8 = (((16u * (unsigned)t) ^ (unsigned)t) << 3);
  float p[16];
#pragma unroll
  for (int c = 0; c < 16; ++c) {
    float2 v = *(const float2*)(sb + (mbase8 ^ ((unsigned)c << 3)));
    p[c] = v.x*v.x + v.y*v.y;
  }
#pragma unroll
  for (int b = 0; b < 4; ++b) {
#pragma unroll
    for (int c = 0; c < 16; ++c) {
      if (!(c & (1 << b))) {
        const int c1 = c | (1 << b);
        float u = p[c], v = p[c1];
        p[c] = u + v; p[c1] = u - v;
      }
    }
  }
  float zs[NQ];
#pragma unroll
  for (int q = 0; q < NQ; ++q) {
    const unsigned m = PLAN.zsel[q];
    const float v = p[m & 15u];
    const int sgn = __popc((unsigned)t & (m >> 4)) & 1;
    zs[q] = sgn ? -v : v;
  }
#pragma unroll
  for (int q = 0; q < NQ; ++q) {
#pragma unroll
    for (int off = 32; off > 0; off >>= 1) zs[q] += __shfl_down(zs[q], off, 64);
  }
  __syncthreads();               // all LDS reads done; safe to reuse sst
  const int w = t >> 6;
  if ((t & 63) == 0) {
#pragma unroll
    for (int q = 0; q < NQ; ++q) sf[w*NQ + q] = zs[q];
    sf[48 + w] = ssq;
  }
  __syncthreads();
  if (t < NQ) {
    const float den = sf[48] + sf[49] + sf[50] + sf[51];
    const float tot = sf[t] + sf[NQ + t] + sf[2*NQ + t] + sf[3*NQ + t];
    out[row * NQ + t] = tot / den;
  }
}

extern "C" void kernel_launch(void* const* d_in, const int* in_sizes, int n_in,
                              void* d_out, int out_size, void* d_ws, size_t ws_size,
                              hipStream_t stream) {
  const float* x = (const float*)d_in[0];
  const float* params = (const float*)d_in[1];
  float* out = (float*)d_out;
  float* gates = (float*)d_ws;                 // 288 floats
  const int nrows = in_sizes[0] / DIM;         // 8192
  qc_prep<<<dim3(1), dim3(64), 0, stream>>>(params, gates);
  qc_main<<<dim3(nrows), dim3(256), 0, stream>>>(x, gates, out);
}

// Round 3
// 570.099 us; speedup vs baseline: 1.1395x; 1.1395x over previous
//
#include <hip/hip_runtime.h>
#include <math.h>

#define NQ 12
#define DIM 4096
#define NGATES 36
#define NROUND 9

// GF(2)-linear LDS swizzle (bijective on 12 bits): sw(a^b) = sw(a)^sw(b)
constexpr unsigned swz(unsigned x) { return x ^ (x >> 4); }

// ---- compile-time circuit plan: CNOTs folded into GF(2) index maps ----
// M: logical index i lives at physical index M(i). CNOT(bc<-ctrl, bt<-tgt):
// M <- M*C (col bc ^= col bt), M^-1 <- C*M^-1 (row bt ^= row bc).
// Gate on logical bit b: pair mask m = M*e_b, "1"-selector = row b of M^-1.
// 4 gates per round (same layer => parity(m_j & s_i) = delta_ij exactly).
struct Round {
  unsigned s[4];       // selectors of the 4 gates
  unsigned l[4];       // sorted pivot low-masks for 4-zero-bit insertion
  unsigned cbsw8[16];  // swizzled byte offsets of the 16 coset slots
};
struct PlanT {
  Round rd[NROUND];
  unsigned zsel[NQ];
};

constexpr PlanT make_plan() {
  PlanT P{};
  unsigned Mcol[NQ] = {}, Minv[NQ] = {};
  for (int i = 0; i < NQ; ++i) { Mcol[i] = 1u << i; Minv[i] = 1u << i; }
  unsigned gm[NGATES] = {}, gs[NGATES] = {};
  int g = 0;
  for (int L = 0; L < 3; ++L) {
    for (int q = 0; q < NQ; ++q) { int b = NQ - 1 - q; gm[g] = Mcol[b]; gs[g] = Minv[b]; ++g; }
    for (int q = 0; q < NQ; ++q) {
      int bc = NQ - 1 - q, bt = NQ - 1 - ((q + 1) % NQ);
      Mcol[bc] ^= Mcol[bt];
      Minv[bt] ^= Minv[bc];
    }
  }
  for (int r = 0; r < NROUND; ++r) {
    unsigned m[4], red[4];
    for (int k = 0; k < 4; ++k) { m[k] = gm[4*r+k]; red[k] = m[k]; P.rd[r].s[k] = gs[4*r+k]; }
    for (int a = 0; a < 4; ++a) {
      unsigned p = red[a] & (0u - red[a]);
      for (int b = a + 1; b < 4; ++b) if (red[b] & p) red[b] ^= red[a];
    }
    unsigned piv[4];
    for (int a = 0; a < 4; ++a) piv[a] = red[a] & (0u - red[a]);
    for (int a = 0; a < 4; ++a)
      for (int b = a + 1; b < 4; ++b)
        if (piv[a] > piv[b]) { unsigned tp = piv[a]; piv[a] = piv[b]; piv[b] = tp; }
    for (int a = 0; a < 4; ++a) P.rd[r].l[a] = piv[a] - 1u;
    for (int d = 0; d < 16; ++d) {
      unsigned c = 0;
      for (int k = 0; k < 4; ++k) if (d & (1 << k)) c ^= m[k];
      P.rd[r].cbsw8[d] = swz(c) << 3;
    }
  }
  for (int q = 0; q < NQ; ++q) P.zsel[q] = Minv[NQ - 1 - q];
  return P;
}

constexpr PlanT PLAN = make_plan();

// ---- prep: fuse U = RZ*RY*RX per (layer,qubit) -> d_ws[288] ----
__global__ void qc_prep(const float* __restrict__ params, float* __restrict__ gates) {
  int t = threadIdx.x;
  if (t < NGATES) {
    float h1 = params[3*t+0]*0.5f, h2 = params[3*t+1]*0.5f, h3 = params[3*t+2]*0.5f;
    float c1 = cosf(h1), s1 = sinf(h1);
    float c2 = cosf(h2), s2 = sinf(h2);
    float c3 = cosf(h3), s3 = sinf(h3);
    float a00r =  c2*c1, a00i =  s2*s1;
    float a01r = -s2*c1, a01i = -c2*s1;
    float a10r =  s2*c1, a10i = -c2*s1;
    float a11r =  c2*c1, a11i = -s2*s1;
    float* u = &gates[t*8];
    u[0] = c3*a00r + s3*a00i;  u[1] = c3*a00i - s3*a00r;
    u[2] = c3*a01r + s3*a01i;  u[3] = c3*a01i - s3*a01r;
    u[4] = c3*a10r - s3*a10i;  u[5] = c3*a10i + s3*a10r;
    u[6] = c3*a11r - s3*a11i;  u[7] = c3*a11i + s3*a11r;
  }
}

__global__ __launch_bounds__(256, 4) void qc_main(
    const float* __restrict__ x, const float* __restrict__ gates,
    float* __restrict__ out) {
  __shared__ float2 sst[DIM];       // 32768 B state
  __shared__ float su[NGATES * 8];  // 1152 B fused gate matrices
  __shared__ float sred[64];        // 256 B reductions
  char* sb = (char*)sst;
  const int t = threadIdx.x;
  const long row = blockIdx.x;

  // ---- stage gates (broadcast data) into LDS ----
  if (t < 72) ((float4*)su)[t] = ((const float4*)gates)[t];

  // ---- stage x row (im=0), accumulate sum of squares ----
  const float4* x4 = (const float4*)(x + (size_t)row * DIM);
  float ssq = 0.f;
#pragma unroll
  for (int k = 0; k < 4; ++k) {
    float4 a = x4[t + 256*k];
    int j0 = 4*(t + 256*k);
    *(float2*)(sb + (swz((unsigned)j0)     << 3)) = make_float2(a.x, 0.f);
    *(float2*)(sb + (swz((unsigned)(j0+1)) << 3)) = make_float2(a.y, 0.f);
    *(float2*)(sb + (swz((unsigned)(j0+2)) << 3)) = make_float2(a.z, 0.f);
    *(float2*)(sb + (swz((unsigned)(j0+3)) << 3)) = make_float2(a.w, 0.f);
    ssq += a.x*a.x + a.y*a.y + a.z*a.z + a.w*a.w;
  }
#pragma unroll
  for (int off = 32; off > 0; off >>= 1) ssq += __shfl_down(ssq, off, 64);
  __syncthreads();

  // ---- 9 rounds of 4 generalized-bit gates; one LDS round-trip each ----
#pragma unroll
  for (int r = 0; r < NROUND; ++r) {
    unsigned j = (unsigned)t;
    j = ((j & ~PLAN.rd[r].l[0]) << 1) | (j & PLAN.rd[r].l[0]);
    j = ((j & ~PLAN.rd[r].l[1]) << 1) | (j & PLAN.rd[r].l[1]);
    j = ((j & ~PLAN.rd[r].l[2]) << 1) | (j & PLAN.rd[r].l[2]);
    j = ((j & ~PLAN.rd[r].l[3]) << 1) | (j & PLAN.rd[r].l[3]);
    // relabel (in swizzled-byte domain; swizzle is GF(2)-linear)
    unsigned adj8 = 0;
    adj8 ^= (unsigned)(-(int)(__popc(j & PLAN.rd[r].s[0]) & 1)) & PLAN.rd[r].cbsw8[1];
    adj8 ^= (unsigned)(-(int)(__popc(j & PLAN.rd[r].s[1]) & 1)) & PLAN.rd[r].cbsw8[2];
    adj8 ^= (unsigned)(-(int)(__popc(j & PLAN.rd[r].s[2]) & 1)) & PLAN.rd[r].cbsw8[4];
    adj8 ^= (unsigned)(-(int)(__popc(j & PLAN.rd[r].s[3]) & 1)) & PLAN.rd[r].cbsw8[8];
    const unsigned base8 = ((j ^ (j >> 4)) << 3) ^ adj8;

    float ar[16], ai[16];
#pragma unroll
    for (int d = 0; d < 16; ++d) {
      float2 v = *(const float2*)(sb + (base8 ^ PLAN.rd[r].cbsw8[d]));
      ar[d] = v.x; ai[d] = v.y;
    }
    const float4* gq = (const float4*)(su + r*32);
#pragma unroll
    for (int st = 0; st < 4; ++st) {
      const float4 ua = gq[st*2], ub = gq[st*2+1];
      const float u0 = ua.x, u1 = ua.y, u2 = ua.z, u3 = ua.w;
      const float u4 = ub.x, u5 = ub.y, u6 = ub.z, u7 = ub.w;
#pragma unroll
      for (int d = 0; d < 16; ++d) {
        if (!(d & (1 << st))) {
          const int d1 = d | (1 << st);
          float a0r = ar[d], a0i = ai[d], a1r = ar[d1], a1i = ai[d1];
          ar[d]  = u0*a0r - u1*a0i + u2*a1r - u3*a1i;
          ai[d]  = u0*a0i + u1*a0r + u2*a1i + u3*a1r;
          ar[d1] = u4*a0r - u5*a0i + u6*a1r - u7*a1i;
          ai[d1] = u4*a0i + u5*a0r + u6*a1i + u7*a1r;
        }
      }
    }
#pragma unroll
    for (int d = 0; d < 16; ++d)
      *(float2*)(sb + (base8 ^ PLAN.rd[r].cbsw8[d])) = make_float2(ar[d], ai[d]);
    __syncthreads();
  }

  // ---- measurement: 16 consecutive amps/thread, WHT over low 4 bits ----
  const unsigned mbase8 = (((16u * (unsigned)t) ^ (unsigned)t) << 3);
  float p[16];
#pragma unroll
  for (int c = 0; c < 16; ++c) {
    float2 v = *(const float2*)(sb + (mbase8 ^ ((unsigned)c << 3)));
    p[c] = v.x*v.x + v.y*v.y;
  }
#pragma unroll
  for (int b = 0; b < 4; ++b) {
#pragma unroll
    for (int c = 0; c < 16; ++c) {
      if (!(c & (1 << b))) {
        const int c1 = c | (1 << b);
        float u = p[c], v = p[c1];
        p[c] = u + v; p[c1] = u - v;
      }
    }
  }
  float zs[NQ];
#pragma unroll
  for (int q = 0; q < NQ; ++q) {
    const unsigned m = PLAN.zsel[q];
    const float v = p[m & 15u];
    const int sgn = __popc((unsigned)t & (m >> 4)) & 1;
    zs[q] = sgn ? -v : v;
  }
#pragma unroll
  for (int q = 0; q < NQ; ++q) {
#pragma unroll
    for (int off = 32; off > 0; off >>= 1) zs[q] += __shfl_down(zs[q], off, 64);
  }
  const int w = t >> 6;
  if ((t & 63) == 0) {
#pragma unroll
    for (int q = 0; q < NQ; ++q) sred[w*NQ + q] = zs[q];
    sred[48 + w] = ssq;
  }
  __syncthreads();
  if (t < NQ) {
    const float den = sred[48] + sred[49] + sred[50] + sred[51];
    const float tot = sred[t] + sred[NQ + t] + sred[2*NQ + t] + sred[3*NQ + t];
    out[row * NQ + t] = tot / den;
  }
}

extern "C" void kernel_launch(void* const* d_in, const int* in_sizes, int n_in,
                              void* d_out, int out_size, void* d_ws, size_t ws_size,
                              hipStream_t stream) {
  const float* x = (const float*)d_in[0];
  const float* params = (const float*)d_in[1];
  float* out = (float*)d_out;
  float* gates = (float*)d_ws;                 // 288 floats
  const int nrows = in_sizes[0] / DIM;         // 8192
  qc_prep<<<dim3(1), dim3(64), 0, stream>>>(params, gates);
  qc_main<<<dim3(nrows), dim3(256), 0, stream>>>(x, gates, out);
}

// Round 4
// 509.286 us; speedup vs baseline: 1.2755x; 1.1194x over previous
//
#include <hip/hip_runtime.h>
#include <math.h>

#define NQ 12
#define DIM 4096
#define NGATES 36
#define NROUND 9

// GF(2)-linear LDS swizzle (bijective on 12 bits): sw(a^b) = sw(a)^sw(b)
constexpr unsigned swz(unsigned x) { return x ^ (x >> 4); }

// ---- compile-time circuit plan: CNOTs folded into GF(2) index maps ----
// M: logical index i lives at physical index M(i). CNOT(bc<-ctrl, bt<-tgt):
// M <- M*C (col bc ^= col bt), M^-1 <- C*M^-1 (row bt ^= row bc).
// Gate on logical bit b: pair mask m = M*e_b, "1"-selector = row b of M^-1.
// 4 gates per round (same layer => parity(m_j & s_i) = delta_ij exactly).
struct Round {
  unsigned s[4];       // selectors of the 4 gates
  unsigned l[4];       // sorted pivot low-masks for 4-zero-bit insertion
  unsigned cbsw8[16];  // swizzled byte offsets of the 16 coset slots
};
struct PlanT {
  Round rd[NROUND];
  unsigned zsel[NQ];
};

constexpr PlanT make_plan() {
  PlanT P{};
  unsigned Mcol[NQ] = {}, Minv[NQ] = {};
  for (int i = 0; i < NQ; ++i) { Mcol[i] = 1u << i; Minv[i] = 1u << i; }
  unsigned gm[NGATES] = {}, gs[NGATES] = {};
  int g = 0;
  for (int L = 0; L < 3; ++L) {
    for (int q = 0; q < NQ; ++q) { int b = NQ - 1 - q; gm[g] = Mcol[b]; gs[g] = Minv[b]; ++g; }
    for (int q = 0; q < NQ; ++q) {
      int bc = NQ - 1 - q, bt = NQ - 1 - ((q + 1) % NQ);
      Mcol[bc] ^= Mcol[bt];
      Minv[bt] ^= Minv[bc];
    }
  }
  for (int r = 0; r < NROUND; ++r) {
    unsigned m[4], red[4];
    for (int k = 0; k < 4; ++k) { m[k] = gm[4*r+k]; red[k] = m[k]; P.rd[r].s[k] = gs[4*r+k]; }
    for (int a = 0; a < 4; ++a) {
      unsigned p = red[a] & (0u - red[a]);
      for (int b = a + 1; b < 4; ++b) if (red[b] & p) red[b] ^= red[a];
    }
    unsigned piv[4];
    for (int a = 0; a < 4; ++a) piv[a] = red[a] & (0u - red[a]);
    for (int a = 0; a < 4; ++a)
      for (int b = a + 1; b < 4; ++b)
        if (piv[a] > piv[b]) { unsigned tp = piv[a]; piv[a] = piv[b]; piv[b] = tp; }
    for (int a = 0; a < 4; ++a) P.rd[r].l[a] = piv[a] - 1u;
    for (int d = 0; d < 16; ++d) {
      unsigned c = 0;
      for (int k = 0; k < 4; ++k) if (d & (1 << k)) c ^= m[k];
      P.rd[r].cbsw8[d] = swz(c) << 3;
    }
  }
  for (int q = 0; q < NQ; ++q) P.zsel[q] = Minv[NQ - 1 - q];
  return P;
}

constexpr PlanT PLAN = make_plan();

// ---- prep: fuse U = RZ*RY*RX per (layer,qubit) -> d_ws[288] ----
__global__ void qc_prep(const float* __restrict__ params, float* __restrict__ gates) {
  int t = threadIdx.x;
  if (t < NGATES) {
    float h1 = params[3*t+0]*0.5f, h2 = params[3*t+1]*0.5f, h3 = params[3*t+2]*0.5f;
    float c1 = cosf(h1), s1 = sinf(h1);
    float c2 = cosf(h2), s2 = sinf(h2);
    float c3 = cosf(h3), s3 = sinf(h3);
    float a00r =  c2*c1, a00i =  s2*s1;
    float a01r = -s2*c1, a01i = -c2*s1;
    float a10r =  s2*c1, a10i = -c2*s1;
    float a11r =  c2*c1, a11i = -s2*s1;
    float* u = &gates[t*8];
    u[0] = c3*a00r + s3*a00i;  u[1] = c3*a00i - s3*a00r;
    u[2] = c3*a01r + s3*a01i;  u[3] = c3*a01i - s3*a01r;
    u[4] = c3*a10r - s3*a10i;  u[5] = c3*a10i + s3*a10r;
    u[6] = c3*a11r - s3*a11i;  u[7] = c3*a11i + s3*a11r;
  }
}

__global__ __launch_bounds__(256, 4) void qc_main(
    const float* __restrict__ x, const float* __restrict__ gates,
    float* __restrict__ out) {
  __shared__ float2 sst[DIM];       // 32768 B state
  __shared__ float su[NGATES * 8];  // 1152 B fused gate matrices
  __shared__ float sred[64];        // 256 B reductions
  char* sb = (char*)sst;
  const int t = threadIdx.x;
  const long row = blockIdx.x;

  // ---- stage gates (broadcast data) into LDS ----
  if (t < 72) ((float4*)su)[t] = ((const float4*)gates)[t];

  // ---- stage x row (im=0), accumulate sum of squares ----
  const float4* x4 = (const float4*)(x + (size_t)row * DIM);
  float ssq = 0.f;
#pragma unroll
  for (int k = 0; k < 4; ++k) {
    float4 a = x4[t + 256*k];
    int j0 = 4*(t + 256*k);
    *(float2*)(sb + (swz((unsigned)j0)     << 3)) = make_float2(a.x, 0.f);
    *(float2*)(sb + (swz((unsigned)(j0+1)) << 3)) = make_float2(a.y, 0.f);
    *(float2*)(sb + (swz((unsigned)(j0+2)) << 3)) = make_float2(a.z, 0.f);
    *(float2*)(sb + (swz((unsigned)(j0+3)) << 3)) = make_float2(a.w, 0.f);
    ssq += a.x*a.x + a.y*a.y + a.z*a.z + a.w*a.w;
  }
#pragma unroll
  for (int off = 32; off > 0; off >>= 1) ssq += __shfl_down(ssq, off, 64);
  __syncthreads();

  // ---- 9 rounds of 4 generalized-bit gates; one LDS round-trip each ----
  // unroll 1: one round's live set (~55 regs) fits without spilling; full
  // unroll let the scheduler interleave rounds -> 340 MB scratch traffic (R3).
#pragma unroll 1
  for (int r = 0; r < NROUND; ++r) {
    // uniform scalar loads of this round's plan (SGPRs)
    unsigned s0 = PLAN.rd[r].s[0], sA = PLAN.rd[r].s[1];
    unsigned sB = PLAN.rd[r].s[2], sC = PLAN.rd[r].s[3];
    unsigned l0 = PLAN.rd[r].l[0], l1 = PLAN.rd[r].l[1];
    unsigned l2 = PLAN.rd[r].l[2], l3 = PLAN.rd[r].l[3];
    unsigned cb[16];
#pragma unroll
    for (int d = 0; d < 16; ++d) cb[d] = PLAN.rd[r].cbsw8[d];

    unsigned j = (unsigned)t;
    j = ((j & ~l0) << 1) | (j & l0);
    j = ((j & ~l1) << 1) | (j & l1);
    j = ((j & ~l2) << 1) | (j & l2);
    j = ((j & ~l3) << 1) | (j & l3);
    // relabel (in swizzled-byte domain; swizzle is GF(2)-linear)
    unsigned adj8 = 0;
    adj8 ^= (unsigned)(-(int)(__popc(j & s0) & 1)) & cb[1];
    adj8 ^= (unsigned)(-(int)(__popc(j & sA) & 1)) & cb[2];
    adj8 ^= (unsigned)(-(int)(__popc(j & sB) & 1)) & cb[4];
    adj8 ^= (unsigned)(-(int)(__popc(j & sC) & 1)) & cb[8];
    const unsigned base8 = ((j ^ (j >> 4)) << 3) ^ adj8;

    float ar[16], ai[16];
#pragma unroll
    for (int d = 0; d < 16; ++d) {
      float2 v = *(const float2*)(sb + (base8 ^ cb[d]));
      ar[d] = v.x; ai[d] = v.y;
    }
    const float4* gq = (const float4*)(su + r*32);
#pragma unroll
    for (int st = 0; st < 4; ++st) {
      const float4 ua = gq[st*2], ub = gq[st*2+1];
      const float u0 = ua.x, u1 = ua.y, u2 = ua.z, u3 = ua.w;
      const float u4 = ub.x, u5 = ub.y, u6 = ub.z, u7 = ub.w;
#pragma unroll
      for (int d = 0; d < 16; ++d) {
        if (!(d & (1 << st))) {
          const int d1 = d | (1 << st);
          float a0r = ar[d], a0i = ai[d], a1r = ar[d1], a1i = ai[d1];
          ar[d]  = u0*a0r - u1*a0i + u2*a1r - u3*a1i;
          ai[d]  = u0*a0i + u1*a0r + u2*a1i + u3*a1r;
          ar[d1] = u4*a0r - u5*a0i + u6*a1r - u7*a1i;
          ai[d1] = u4*a0i + u5*a0r + u6*a1i + u7*a1r;
        }
      }
    }
#pragma unroll
    for (int d = 0; d < 16; ++d)
      *(float2*)(sb + (base8 ^ cb[d])) = make_float2(ar[d], ai[d]);
    __syncthreads();
  }

  // ---- measurement: 16 consecutive amps/thread, WHT over low 4 bits ----
  const unsigned mbase8 = (((16u * (unsigned)t) ^ (unsigned)t) << 3);
  float p[16];
#pragma unroll
  for (int c = 0; c < 16; ++c) {
    float2 v = *(const float2*)(sb + (mbase8 ^ ((unsigned)c << 3)));
    p[c] = v.x*v.x + v.y*v.y;
  }
#pragma unroll
  for (int b = 0; b < 4; ++b) {
#pragma unroll
    for (int c = 0; c < 16; ++c) {
      if (!(c & (1 << b))) {
        const int c1 = c | (1 << b);
        float u = p[c], v = p[c1];
        p[c] = u + v; p[c1] = u - v;
      }
    }
  }
  float zs[NQ];
#pragma unroll
  for (int q = 0; q < NQ; ++q) {
    const unsigned m = PLAN.zsel[q];
    const float v = p[m & 15u];
    const int sgn = __popc((unsigned)t & (m >> 4)) & 1;
    zs[q] = sgn ? -v : v;
  }
#pragma unroll
  for (int q = 0; q < NQ; ++q) {
#pragma unroll
    for (int off = 32; off > 0; off >>= 1) zs[q] += __shfl_down(zs[q], off, 64);
  }
  const int w = t >> 6;
  if ((t & 63) == 0) {
#pragma unroll
    for (int q = 0; q < NQ; ++q) sred[w*NQ + q] = zs[q];
    sred[48 + w] = ssq;
  }
  __syncthreads();
  if (t < NQ) {
    const float den = sred[48] + sred[49] + sred[50] + sred[51];
    const float tot = sred[t] + sred[NQ + t] + sred[2*NQ + t] + sred[3*NQ + t];
    out[row * NQ + t] = tot / den;
  }
}

extern "C" void kernel_launch(void* const* d_in, const int* in_sizes, int n_in,
                              void* d_out, int out_size, void* d_ws, size_t ws_size,
                              hipStream_t stream) {
  const float* x = (const float*)d_in[0];
  const float* params = (const float*)d_in[1];
  float* out = (float*)d_out;
  float* gates = (float*)d_ws;                 // 288 floats
  const int nrows = in_sizes[0] / DIM;         // 8192
  qc_prep<<<dim3(1), dim3(64), 0, stream>>>(params, gates);
  qc_main<<<dim3(nrows), dim3(256), 0, stream>>>(x, gates, out);
}

// Round 5
// 381.736 us; speedup vs baseline: 1.7017x; 1.3341x over previous
//
#include <hip/hip_runtime.h>
#include <math.h>

#define NQ 12
#define DIM 4096
#define NGATES 36
#define NROUND 9

typedef float f32x2 __attribute__((ext_vector_type(2)));

// GF(2)-linear LDS swizzle (bijective on 12 bits): sw(a^b) = sw(a)^sw(b)
constexpr unsigned swz(unsigned x) { return x ^ (x >> 4); }

// ---- compile-time circuit plan: CNOTs folded into GF(2) index maps ----
// M: logical index i lives at physical index M(i). CNOT(bc<-ctrl, bt<-tgt):
// M <- M*C (col bc ^= col bt), M^-1 <- C*M^-1 (row bt ^= row bc).
// Gate on logical bit b: pair mask m = M*e_b, "1"-selector = row b of M^-1.
// 4 gates per round (same layer => parity(m_j & s_i) = delta_ij exactly).
struct Round {
  unsigned s[4];       // selectors of the 4 gates
  unsigned l[4];       // sorted pivot low-masks for 4-zero-bit insertion
  unsigned cbsw8[16];  // swizzled byte offsets of the 16 coset slots
};
struct PlanT {
  Round rd[NROUND];
  unsigned zsel[NQ];
};

constexpr PlanT make_plan() {
  PlanT P{};
  unsigned Mcol[NQ] = {}, Minv[NQ] = {};
  for (int i = 0; i < NQ; ++i) { Mcol[i] = 1u << i; Minv[i] = 1u << i; }
  unsigned gm[NGATES] = {}, gs[NGATES] = {};
  int g = 0;
  for (int L = 0; L < 3; ++L) {
    for (int q = 0; q < NQ; ++q) { int b = NQ - 1 - q; gm[g] = Mcol[b]; gs[g] = Minv[b]; ++g; }
    for (int q = 0; q < NQ; ++q) {
      int bc = NQ - 1 - q, bt = NQ - 1 - ((q + 1) % NQ);
      Mcol[bc] ^= Mcol[bt];
      Minv[bt] ^= Minv[bc];
    }
  }
  for (int r = 0; r < NROUND; ++r) {
    unsigned m[4], red[4];
    for (int k = 0; k < 4; ++k) { m[k] = gm[4*r+k]; red[k] = m[k]; P.rd[r].s[k] = gs[4*r+k]; }
    for (int a = 0; a < 4; ++a) {
      unsigned p = red[a] & (0u - red[a]);
      for (int b = a + 1; b < 4; ++b) if (red[b] & p) red[b] ^= red[a];
    }
    unsigned piv[4];
    for (int a = 0; a < 4; ++a) piv[a] = red[a] & (0u - red[a]);
    for (int a = 0; a < 4; ++a)
      for (int b = a + 1; b < 4; ++b)
        if (piv[a] > piv[b]) { unsigned tp = piv[a]; piv[a] = piv[b]; piv[b] = tp; }
    for (int a = 0; a < 4; ++a) P.rd[r].l[a] = piv[a] - 1u;
    for (int d = 0; d < 16; ++d) {
      unsigned c = 0;
      for (int k = 0; k < 4; ++k) if (d & (1 << k)) c ^= m[k];
      P.rd[r].cbsw8[d] = swz(c) << 3;
    }
  }
  for (int q = 0; q < NQ; ++q) P.zsel[q] = Minv[NQ - 1 - q];
  return P;
}

constexpr PlanT PLAN = make_plan();

// ---- prep: fuse U = RZ*RY*RX per (layer,qubit) -> d_ws[288] ----
__global__ void qc_prep(const float* __restrict__ params, float* __restrict__ gates) {
  int t = threadIdx.x;
  if (t < NGATES) {
    float h1 = params[3*t+0]*0.5f, h2 = params[3*t+1]*0.5f, h3 = params[3*t+2]*0.5f;
    float c1 = cosf(h1), s1 = sinf(h1);
    float c2 = cosf(h2), s2 = sinf(h2);
    float c3 = cosf(h3), s3 = sinf(h3);
    float a00r =  c2*c1, a00i =  s2*s1;
    float a01r = -s2*c1, a01i = -c2*s1;
    float a10r =  s2*c1, a10i = -c2*s1;
    float a11r =  c2*c1, a11i = -s2*s1;
    float* u = &gates[t*8];
    u[0] = c3*a00r + s3*a00i;  u[1] = c3*a00i - s3*a00r;
    u[2] = c3*a01r + s3*a01i;  u[3] = c3*a01i - s3*a01r;
    u[4] = c3*a10r - s3*a10i;  u[5] = c3*a10i + s3*a10r;
    u[6] = c3*a11r - s3*a11i;  u[7] = c3*a11i + s3*a11r;
  }
}

__device__ __forceinline__ f32x2 blo(f32x2 a) { return __builtin_shufflevector(a, a, 0, 0); }
__device__ __forceinline__ f32x2 bhi(f32x2 a) { return __builtin_shufflevector(a, a, 1, 1); }

__global__ __launch_bounds__(256)
__attribute__((amdgpu_waves_per_eu(4, 4)))
void qc_main(const float* __restrict__ x, const float* __restrict__ gates,
             float* __restrict__ out) {
  __shared__ float2 sst[DIM];        // 32768 B state (re,im packed)
  __shared__ f32x2 supk[NGATES * 8]; // 2304 B packed gate coeffs
  __shared__ float sred[64];         // 256 B reductions
  char* sb = (char*)sst;
  const int t = threadIdx.x;
  const long row = blockIdx.x;

  // ---- build packed coefficient pairs in LDS ----
  // gate u[8] -> 8 packed: (u0,u1),(-u1,u0),(u2,u3),(-u3,u2),(u4,u5),(-u5,u4),(u6,u7),(-u7,u6)
  for (int p = t; p < NGATES * 8; p += 256) {
    const int g = p >> 3, k = p & 7;
    const float* u = gates + g * 8;
    f32x2 c;
    if (k & 1) { c[0] = -u[k]; c[1] = u[k-1]; }
    else       { c[0] =  u[k]; c[1] = u[k+1]; }
    supk[p] = c;
  }

  // ---- stage x row (im=0), accumulate sum of squares ----
  const float4* x4 = (const float4*)(x + (size_t)row * DIM);
  float ssq = 0.f;
#pragma unroll
  for (int k = 0; k < 4; ++k) {
    float4 a = x4[t + 256*k];
    int j0 = 4*(t + 256*k);
    *(float2*)(sb + (swz((unsigned)j0)     << 3)) = make_float2(a.x, 0.f);
    *(float2*)(sb + (swz((unsigned)(j0+1)) << 3)) = make_float2(a.y, 0.f);
    *(float2*)(sb + (swz((unsigned)(j0+2)) << 3)) = make_float2(a.z, 0.f);
    *(float2*)(sb + (swz((unsigned)(j0+3)) << 3)) = make_float2(a.w, 0.f);
    ssq += a.x*a.x + a.y*a.y + a.z*a.z + a.w*a.w;
  }
#pragma unroll
  for (int off = 32; off > 0; off >>= 1) ssq += __shfl_down(ssq, off, 64);
  __syncthreads();

  // ---- 9 rounds of 4 generalized-bit gates; one LDS round-trip each ----
  // unroll 1: one round's live set fits in the 128-VGPR budget (4 waves/EU).
#pragma unroll 1
  for (int r = 0; r < NROUND; ++r) {
    const unsigned s0 = PLAN.rd[r].s[0], sA = PLAN.rd[r].s[1];
    const unsigned sB = PLAN.rd[r].s[2], sC = PLAN.rd[r].s[3];
    const unsigned l0 = PLAN.rd[r].l[0], l1 = PLAN.rd[r].l[1];
    const unsigned l2 = PLAN.rd[r].l[2], l3 = PLAN.rd[r].l[3];
    unsigned cb[16];
#pragma unroll
    for (int d = 0; d < 16; ++d) cb[d] = PLAN.rd[r].cbsw8[d];

    unsigned j = (unsigned)t;
    j = ((j & ~l0) << 1) | (j & l0);
    j = ((j & ~l1) << 1) | (j & l1);
    j = ((j & ~l2) << 1) | (j & l2);
    j = ((j & ~l3) << 1) | (j & l3);
    // relabel (swizzled-byte domain; swizzle is GF(2)-linear)
    unsigned adj8 = 0;
    adj8 ^= (unsigned)(-(int)(__popc(j & s0) & 1)) & cb[1];
    adj8 ^= (unsigned)(-(int)(__popc(j & sA) & 1)) & cb[2];
    adj8 ^= (unsigned)(-(int)(__popc(j & sB) & 1)) & cb[4];
    adj8 ^= (unsigned)(-(int)(__popc(j & sC) & 1)) & cb[8];
    const unsigned base8 = ((j ^ (j >> 4)) << 3) ^ adj8;

    f32x2 v[16];
#pragma unroll
    for (int d = 0; d < 16; ++d)
      v[d] = *(const f32x2*)(sb + (base8 ^ cb[d]));

#pragma unroll
    for (int st = 0; st < 4; ++st) {
      const f32x2* cp = &supk[(r * 4 + st) * 8];
      const f32x2 c0 = cp[0], c1 = cp[1], c2 = cp[2], c3 = cp[3];
      const f32x2 c4 = cp[4], c5 = cp[5], c6 = cp[6], c7 = cp[7];
#pragma unroll
      for (int d = 0; d < 16; ++d) {
        if (!(d & (1 << st))) {
          const int d1 = d | (1 << st);
          const f32x2 a0 = v[d], a1 = v[d1];
          f32x2 o0 = c0 * blo(a0);
          o0 += c1 * bhi(a0);
          o0 += c2 * blo(a1);
          o0 += c3 * bhi(a1);
          f32x2 o1 = c4 * blo(a0);
          o1 += c5 * bhi(a0);
          o1 += c6 * blo(a1);
          o1 += c7 * bhi(a1);
          v[d] = o0; v[d1] = o1;
        }
      }
    }
#pragma unroll
    for (int d = 0; d < 16; ++d)
      *(f32x2*)(sb + (base8 ^ cb[d])) = v[d];
    __syncthreads();
  }

  // ---- measurement: 16 consecutive amps/thread, WHT over low 4 bits ----
  const unsigned mbase8 = (((16u * (unsigned)t) ^ (unsigned)t) << 3);
  float p[16];
#pragma unroll
  for (int c = 0; c < 16; ++c) {
    f32x2 v = *(const f32x2*)(sb + (mbase8 ^ ((unsigned)c << 3)));
    f32x2 sq = v * v;
    p[c] = sq[0] + sq[1];
  }
#pragma unroll
  for (int b = 0; b < 4; ++b) {
#pragma unroll
    for (int c = 0; c < 16; ++c) {
      if (!(c & (1 << b))) {
        const int c1 = c | (1 << b);
        float u = p[c], v = p[c1];
        p[c] = u + v; p[c1] = u - v;
      }
    }
  }
  float zs[NQ];
#pragma unroll
  for (int q = 0; q < NQ; ++q) {
    const unsigned m = PLAN.zsel[q];
    const float v = p[m & 15u];
    const int sgn = __popc((unsigned)t & (m >> 4)) & 1;
    zs[q] = sgn ? -v : v;
  }
#pragma unroll
  for (int q = 0; q < NQ; ++q) {
#pragma unroll
    for (int off = 32; off > 0; off >>= 1) zs[q] += __shfl_down(zs[q], off, 64);
  }
  const int w = t >> 6;
  if ((t & 63) == 0) {
#pragma unroll
    for (int q = 0; q < NQ; ++q) sred[w*NQ + q] = zs[q];
    sred[48 + w] = ssq;
  }
  __syncthreads();
  if (t < NQ) {
    const float den = sred[48] + sred[49] + sred[50] + sred[51];
    const float tot = sred[t] + sred[NQ + t] + sred[2*NQ + t] + sred[3*NQ + t];
    out[row * NQ + t] = tot / den;
  }
}

extern "C" void kernel_launch(void* const* d_in, const int* in_sizes, int n_in,
                              void* d_out, int out_size, void* d_ws, size_t ws_size,
                              hipStream_t stream) {
  const float* x = (const float*)d_in[0];
  const float* params = (const float*)d_in[1];
  float* out = (float*)d_out;
  float* gates = (float*)d_ws;                 // 288 floats
  const int nrows = in_sizes[0] / DIM;         // 8192
  qc_prep<<<dim3(1), dim3(64), 0, stream>>>(params, gates);
  qc_main<<<dim3(nrows), dim3(256), 0, stream>>>(x, gates, out);
}

// Round 6
// 349.346 us; speedup vs baseline: 1.8595x; 1.0927x over previous
//
#include <hip/hip_runtime.h>
#include <math.h>

#define NQ 12
#define DIM 4096
#define NGATES 36
#define NROUND 9

typedef float f32x2 __attribute__((ext_vector_type(2)));

// GF(2)-linear LDS swizzle (bijective on 12 bits): sw(a^b) = sw(a)^sw(b)
constexpr unsigned swz(unsigned x) { return x ^ (x >> 4); }

// ---- compile-time circuit plan: CNOTs folded into GF(2) index maps ----
// M: logical index i lives at physical index M(i). CNOT(bc<-ctrl, bt<-tgt):
// M <- M*C (col bc ^= col bt), M^-1 <- C*M^-1 (row bt ^= row bc).
// Gate on logical bit b: pair mask m = M*e_b, "1"-selector = row b of M^-1.
// 4 gates per round (same layer => parity(m_j & s_i) = delta_ij exactly).
struct Round {
  unsigned s[4];       // selectors of the 4 gates
  unsigned l[4];       // sorted pivot low-masks for 4-zero-bit insertion
  unsigned cbsw8[16];  // swizzled byte offsets of the 16 coset slots
};
struct PlanT {
  Round rd[NROUND];
  unsigned zsel[NQ];
};

constexpr PlanT make_plan() {
  PlanT P{};
  unsigned Mcol[NQ] = {}, Minv[NQ] = {};
  for (int i = 0; i < NQ; ++i) { Mcol[i] = 1u << i; Minv[i] = 1u << i; }
  unsigned gm[NGATES] = {}, gs[NGATES] = {};
  int g = 0;
  for (int L = 0; L < 3; ++L) {
    for (int q = 0; q < NQ; ++q) { int b = NQ - 1 - q; gm[g] = Mcol[b]; gs[g] = Minv[b]; ++g; }
    for (int q = 0; q < NQ; ++q) {
      int bc = NQ - 1 - q, bt = NQ - 1 - ((q + 1) % NQ);
      Mcol[bc] ^= Mcol[bt];
      Minv[bt] ^= Minv[bc];
    }
  }
  for (int r = 0; r < NROUND; ++r) {
    unsigned m[4], red[4];
    for (int k = 0; k < 4; ++k) { m[k] = gm[4*r+k]; red[k] = m[k]; P.rd[r].s[k] = gs[4*r+k]; }
    for (int a = 0; a < 4; ++a) {
      unsigned p = red[a] & (0u - red[a]);
      for (int b = a + 1; b < 4; ++b) if (red[b] & p) red[b] ^= red[a];
    }
    unsigned piv[4];
    for (int a = 0; a < 4; ++a) piv[a] = red[a] & (0u - red[a]);
    for (int a = 0; a < 4; ++a)
      for (int b = a + 1; b < 4; ++b)
        if (piv[a] > piv[b]) { unsigned tp = piv[a]; piv[a] = piv[b]; piv[b] = tp; }
    for (int a = 0; a < 4; ++a) P.rd[r].l[a] = piv[a] - 1u;
    for (int d = 0; d < 16; ++d) {
      unsigned c = 0;
      for (int k = 0; k < 4; ++k) if (d & (1 << k)) c ^= m[k];
      P.rd[r].cbsw8[d] = swz(c) << 3;
    }
  }
  for (int q = 0; q < NQ; ++q) P.zsel[q] = Minv[NQ - 1 - q];
  return P;
}

constexpr PlanT PLAN = make_plan();

// ---- prep: fuse U = RZ*RY*RX per (layer,qubit), emit 8 pre-negated packed
// coefficient pairs per gate -> d_ws[36*8 f32x2] ----
// (u0,u1),(-u1,u0),(u2,u3),(-u3,u2),(u4,u5),(-u5,u4),(u6,u7),(-u7,u6)
__global__ void qc_prep(const float* __restrict__ params, f32x2* __restrict__ gpk) {
  int t = threadIdx.x;
  if (t < NGATES) {
    float h1 = params[3*t+0]*0.5f, h2 = params[3*t+1]*0.5f, h3 = params[3*t+2]*0.5f;
    float c1 = cosf(h1), s1 = sinf(h1);
    float c2 = cosf(h2), s2 = sinf(h2);
    float c3 = cosf(h3), s3 = sinf(h3);
    float a00r =  c2*c1, a00i =  s2*s1;
    float a01r = -s2*c1, a01i = -c2*s1;
    float a10r =  s2*c1, a10i = -c2*s1;
    float a11r =  c2*c1, a11i = -s2*s1;
    float u[8];
    u[0] = c3*a00r + s3*a00i;  u[1] = c3*a00i - s3*a00r;
    u[2] = c3*a01r + s3*a01i;  u[3] = c3*a01i - s3*a01r;
    u[4] = c3*a10r - s3*a10i;  u[5] = c3*a10i + s3*a10r;
    u[6] = c3*a11r - s3*a11i;  u[7] = c3*a11i + s3*a11r;
    f32x2* o = gpk + t*8;
#pragma unroll
    for (int k = 0; k < 4; ++k) {
      f32x2 a, b;
      a[0] =  u[2*k];   a[1] = u[2*k+1];
      b[0] = -u[2*k+1]; b[1] = u[2*k];
      o[2*k]   = a;
      o[2*k+1] = b;
    }
  }
}

__device__ __forceinline__ f32x2 blo(f32x2 a) { return __builtin_shufflevector(a, a, 0, 0); }
__device__ __forceinline__ f32x2 bhi(f32x2 a) { return __builtin_shufflevector(a, a, 1, 1); }

__global__ __launch_bounds__(256)
__attribute__((amdgpu_waves_per_eu(5, 5)))
void qc_main(const float* __restrict__ x, const f32x2* __restrict__ gpk,
             float* __restrict__ out) {
  __shared__ float2 sst[DIM];        // exactly 32768 B -> 5 blocks/CU
  char* sb = (char*)sst;
  float* sf = (float*)sst;           // reduction scratch overlaid post-barrier
  const int t = threadIdx.x;
  const long row = blockIdx.x;

  // ---- stage x row (im=0), accumulate sum of squares ----
  const float4* x4 = (const float4*)(x + (size_t)row * DIM);
  float ssq = 0.f;
#pragma unroll
  for (int k = 0; k < 4; ++k) {
    float4 a = x4[t + 256*k];
    int j0 = 4*(t + 256*k);
    *(float2*)(sb + (swz((unsigned)j0)     << 3)) = make_float2(a.x, 0.f);
    *(float2*)(sb + (swz((unsigned)(j0+1)) << 3)) = make_float2(a.y, 0.f);
    *(float2*)(sb + (swz((unsigned)(j0+2)) << 3)) = make_float2(a.z, 0.f);
    *(float2*)(sb + (swz((unsigned)(j0+3)) << 3)) = make_float2(a.w, 0.f);
    ssq += a.x*a.x + a.y*a.y + a.z*a.z + a.w*a.w;
  }
#pragma unroll
  for (int off = 32; off > 0; off >>= 1) ssq += __shfl_down(ssq, off, 64);
  __syncthreads();

  // ---- 9 rounds of 4 generalized-bit gates; one LDS round-trip each ----
  // unroll 1: one round's live set fits the 102-VGPR budget (5 waves/EU).
#pragma unroll 1
  for (int r = 0; r < NROUND; ++r) {
    const unsigned s0 = PLAN.rd[r].s[0], sA = PLAN.rd[r].s[1];
    const unsigned sB = PLAN.rd[r].s[2], sC = PLAN.rd[r].s[3];
    const unsigned l0 = PLAN.rd[r].l[0], l1 = PLAN.rd[r].l[1];
    const unsigned l2 = PLAN.rd[r].l[2], l3 = PLAN.rd[r].l[3];
    unsigned cb[16];
#pragma unroll
    for (int d = 0; d < 16; ++d) cb[d] = PLAN.rd[r].cbsw8[d];

    unsigned j = (unsigned)t;
    j = ((j & ~l0) << 1) | (j & l0);
    j = ((j & ~l1) << 1) | (j & l1);
    j = ((j & ~l2) << 1) | (j & l2);
    j = ((j & ~l3) << 1) | (j & l3);
    // relabel (swizzled-byte domain; swizzle is GF(2)-linear)
    unsigned adj8 = 0;
    adj8 ^= (unsigned)(-(int)(__popc(j & s0) & 1)) & cb[1];
    adj8 ^= (unsigned)(-(int)(__popc(j & sA) & 1)) & cb[2];
    adj8 ^= (unsigned)(-(int)(__popc(j & sB) & 1)) & cb[4];
    adj8 ^= (unsigned)(-(int)(__popc(j & sC) & 1)) & cb[8];
    const unsigned base8 = ((j ^ (j >> 4)) << 3) ^ adj8;

    f32x2 v[16];
#pragma unroll
    for (int d = 0; d < 16; ++d)
      v[d] = *(const f32x2*)(sb + (base8 ^ cb[d]));

#pragma unroll
    for (int st = 0; st < 4; ++st) {
      // uniform-address coefficient loads (L1-resident; off the DS pipe)
      const f32x2* cp = gpk + (r * 4 + st) * 8;
      const f32x2 c0 = cp[0], c1 = cp[1], c2 = cp[2], c3 = cp[3];
      const f32x2 c4 = cp[4], c5 = cp[5], c6 = cp[6], c7 = cp[7];
#pragma unroll
      for (int d = 0; d < 16; ++d) {
        if (!(d & (1 << st))) {
          const int d1 = d | (1 << st);
          const f32x2 a0 = v[d], a1 = v[d1];
          f32x2 o0 = c0 * blo(a0);
          o0 += c1 * bhi(a0);
          o0 += c2 * blo(a1);
          o0 += c3 * bhi(a1);
          f32x2 o1 = c4 * blo(a0);
          o1 += c5 * bhi(a0);
          o1 += c6 * blo(a1);
          o1 += c7 * bhi(a1);
          v[d] = o0; v[d1] = o1;
        }
      }
    }
#pragma unroll
    for (int d = 0; d < 16; ++d)
      *(f32x2*)(sb + (base8 ^ cb[d])) = v[d];
    __syncthreads();
  }

  // ---- measurement: 16 consecutive amps/thread, WHT over low 4 bits ----
  const unsigned mbase8 = (((16u * (unsigned)t) ^ (unsigned)t) << 3);
  float p[16];
#pragma unroll
  for (int c = 0; c < 16; ++c) {
    f32x2 v = *(const f32x2*)(sb + (mbase8 ^ ((unsigned)c << 3)));
    f32x2 sq = v * v;
    p[c] = sq[0] + sq[1];
  }
#pragma unroll
  for (int b = 0; b < 4; ++b) {
#pragma unroll
    for (int c = 0; c < 16; ++c) {
      if (!(c & (1 << b))) {
        const int c1 = c | (1 << b);
        float u = p[c], v = p[c1];
        p[c] = u + v; p[c1] = u - v;
      }
    }
  }
  float zs[NQ];
#pragma unroll
  for (int q = 0; q < NQ; ++q) {
    const unsigned m = PLAN.zsel[q];
    const float v = p[m & 15u];
    const int sgn = __popc((unsigned)t & (m >> 4)) & 1;
    zs[q] = sgn ? -v : v;
  }
#pragma unroll
  for (int q = 0; q < NQ; ++q) {
#pragma unroll
    for (int off = 32; off > 0; off >>= 1) zs[q] += __shfl_down(zs[q], off, 64);
  }
  __syncthreads();               // all state reads done; safe to overlay sf
  const int w = t >> 6;
  if ((t & 63) == 0) {
#pragma unroll
    for (int q = 0; q < NQ; ++q) sf[w*NQ + q] = zs[q];
    sf[48 + w] = ssq;
  }
  __syncthreads();
  if (t < NQ) {
    const float den = sf[48] + sf[49] + sf[50] + sf[51];
    const float tot = sf[t] + sf[NQ + t] + sf[2*NQ + t] + sf[3*NQ + t];
    out[row * NQ + t] = tot / den;
  }
}

extern "C" void kernel_launch(void* const* d_in, const int* in_sizes, int n_in,
                              void* d_out, int out_size, void* d_ws, size_t ws_size,
                              hipStream_t stream) {
  const float* x = (const float*)d_in[0];
  const float* params = (const float*)d_in[1];
  float* out = (float*)d_out;
  f32x2* gpk = (f32x2*)d_ws;                   // 36*8 packed coeff pairs
  const int nrows = in_sizes[0] / DIM;         // 8192
  qc_prep<<<dim3(1), dim3(64), 0, stream>>>(params, gpk);
  qc_main<<<dim3(nrows), dim3(256), 0, stream>>>(x, gpk, out);
}